// Round 5
// baseline (553.093 us; speedup 1.0000x reference)
//
#include <hip/hip_runtime.h>
#include <math.h>

#define B_  2
#define N_  384
#define C_  256
#define H_  4
#define D_  64
#define NBH (B_*H_)            // 8
#define TSZ (NBH*N_*D_)        // 196608 floats per projected tensor [bh][n][d]
#define ESZ (NBH*N_*N_)        // 1179648 elems per logit matrix
#define SCALE 0.125f           // D^-0.5

typedef _Float16 f16;
typedef f16  f16x8 __attribute__((ext_vector_type(8)));
typedef f16  f16x4 __attribute__((ext_vector_type(4)));
typedef float f32x4 __attribute__((ext_vector_type(4)));

// ---------------------------------------------------------------------------
// Kernel 1: projection. proj[t][bh][n][d], t in {a,b,c,v1,v2}, f32.
// ---------------------------------------------------------------------------
__global__ __launch_bounds__(256) void proj_kernel(const float* __restrict__ x,
                                                   const float* __restrict__ W,
                                                   float* __restrict__ proj) {
    __shared__ float Xs[32][68];
    __shared__ float Ws[32][68];
    const int tid = threadIdx.x;
    const int tx = tid & 15, ty = tid >> 4;
    const int m0 = blockIdx.x * 64;
    const int c0 = blockIdx.y * 64;
    const int t  = c0 >> 8;
    const int wbase = ((t >= 3) ? (t + 3) : t) * 256;

    float acc[4][4] = {{0.f}};
    for (int k0 = 0; k0 < 256; k0 += 32) {
        __syncthreads();
#pragma unroll
        for (int l = 0; l < 8; ++l) {
            const int idx = l * 256 + tid;
            const int mi = idx >> 5, kk = idx & 31;
            Xs[kk][mi] = x[(m0 + mi) * 256 + k0 + kk];
            const int rem = (c0 + mi) & 255;
            Ws[kk][mi] = W[(wbase + rem) * 256 + k0 + kk];
        }
        __syncthreads();
#pragma unroll
        for (int kk = 0; kk < 32; ++kk) {
            const float4 xf = *(const float4*)&Xs[kk][ty * 4];
            const float4 wf = *(const float4*)&Ws[kk][tx * 4];
            const float xa[4] = {xf.x, xf.y, xf.z, xf.w};
            const float wa[4] = {wf.x, wf.y, wf.z, wf.w};
#pragma unroll
            for (int q = 0; q < 4; ++q)
#pragma unroll
                for (int p = 0; p < 4; ++p)
                    acc[q][p] += xa[q] * wa[p];
        }
    }
#pragma unroll
    for (int q = 0; q < 4; ++q) {
        const int r = m0 + ty * 4 + q;
        const int b = r / N_;
        const int n = r - b * N_;
#pragma unroll
        for (int p = 0; p < 4; ++p) {
            const int rem = (c0 + tx * 4 + p) & 255;
            const int h = rem >> 6, d = rem & 63;
            proj[t * TSZ + ((b * H_ + h) * N_ + n) * D_ + d] = acc[q][p];
        }
    }
}

// ---------------------------------------------------------------------------
// Kernel 2: exp-logit matrices, f16, all natural [row][col] layouts.
//  q=0: eAB[bh][i][j]   q=1: eCD[bh][i][k]   q=2: eEF[bh][j][k]
// ---------------------------------------------------------------------------
__global__ __launch_bounds__(256) void logits_kernel(const float* __restrict__ proj,
                                                     f16* __restrict__ eab16,
                                                     f16* __restrict__ ecd16,
                                                     f16* __restrict__ eef16) {
    __shared__ float Xs[32][68];
    __shared__ float Ys[32][68];
    const int tid = threadIdx.x;
    const int tx = tid & 15, ty = tid >> 4;
    const int i0 = blockIdx.x * 64, j0 = blockIdx.y * 64;
    const int q  = blockIdx.z >> 3;
    const int bh = blockIdx.z & 7;
    const int xt = q;
    const int yt = (q == 2) ? 0 : (q + 1);
    const float* Xp = proj + xt * TSZ + bh * N_ * D_;
    const float* Yp = proj + yt * TSZ + bh * N_ * D_;

    float acc[4][4] = {{0.f}};
    for (int k0 = 0; k0 < 64; k0 += 32) {
        __syncthreads();
#pragma unroll
        for (int l = 0; l < 8; ++l) {
            const int idx = l * 256 + tid;
            const int mi = idx >> 5, kk = idx & 31;
            Xs[kk][mi] = Xp[(i0 + mi) * 64 + k0 + kk];
            Ys[kk][mi] = Yp[(j0 + mi) * 64 + k0 + kk];
        }
        __syncthreads();
#pragma unroll
        for (int kk = 0; kk < 32; ++kk) {
            const float4 xf = *(const float4*)&Xs[kk][ty * 4];
            const float4 yf = *(const float4*)&Ys[kk][tx * 4];
            const float xa[4] = {xf.x, xf.y, xf.z, xf.w};
            const float ya[4] = {yf.x, yf.y, yf.z, yf.w};
#pragma unroll
            for (int qq = 0; qq < 4; ++qq)
#pragma unroll
                for (int p = 0; p < 4; ++p)
                    acc[qq][p] += xa[qq] * ya[p];
        }
    }
#pragma unroll
    for (int qq = 0; qq < 4; ++qq)
#pragma unroll
        for (int p = 0; p < 4; ++p) {
            const float e = expf(acc[qq][p] * SCALE);
            const size_t o = (size_t)bh * N_ * N_ + (i0 + ty * 4 + qq) * N_ + j0 + tx * 4 + p;
            if (q == 0)      eab16[o] = (f16)e;
            else if (q == 1) ecd16[o] = (f16)e;
            else             eef16[o] = (f16)e;
        }
}

// ---------------------------------------------------------------------------
// Kernel 2b: transpose v2 to vt2[bh][d][n] f16.
// ---------------------------------------------------------------------------
__global__ __launch_bounds__(256) void vtrans_kernel(const float* __restrict__ proj,
                                                     f16* __restrict__ vt2) {
    __shared__ f16 tile[64][65];
    const int tid = threadIdx.x;
    const int n0 = blockIdx.x * 64;
    const int bh = blockIdx.y;
    const float* src = proj + 4 * TSZ + ((size_t)bh * N_ + n0) * 64;
#pragma unroll
    for (int rep = 0; rep < 16; ++rep) {
        const int idx = rep * 256 + tid;
        const int r = idx >> 6, d = idx & 63;
        tile[d][r] = (f16)src[r * 64 + d];
    }
    __syncthreads();
#pragma unroll
    for (int rep = 0; rep < 16; ++rep) {
        const int idx = rep * 256 + tid;
        const int d = idx >> 6, c = idx & 63;
        vt2[((size_t)bh * 64 + d) * N_ + n0 + c] = tile[d][c];
    }
}

// ---------------------------------------------------------------------------
// Kernel 3 (dominant): Q_i = eEF · W_i with d in the MFMA N-dim.
// Block = (i-chunk 24, j-chunk 64, bh). eEF[jchunk][384] staged once in LDS
// (XOR-swizzled); W_i B-frags built on the fly = eCD[i,k] (broadcast) * v2;
// v2 half register-cached ([4][6] = 96 VGPR), half in LDS (24 KB).
// Per i: 192 MFMAs, fold num[i,d] = sum_j eAB[i,j]*v1[j,d]*Q[j,d] on VALU.
// One barrier per block; non-atomic per-jc partial outputs.
// ---------------------------------------------------------------------------
__global__ __launch_bounds__(256, 2) void triplet_gemm_kernel(
        const f16* __restrict__ eab,   // [bh][i][j]
        const f16* __restrict__ ecd,   // [bh][i][k]
        const f16* __restrict__ eef,   // [bh][j][k]
        const float* __restrict__ v1,  // [bh][n][64] f32
        const f16* __restrict__ vt2,   // [bh][d][n]
        float* __restrict__ numw) {    // [jc][bh][i][64]
    __shared__ __align__(16) f16 eefs[64 * 384];   // 48 KB
    __shared__ __align__(16) f16 v2s[64 * 192];    // 24 KB (k upper half)

    const int tid = threadIdx.x, lane = tid & 63, w = tid >> 6;
    const int quad = lane >> 4, lr = lane & 15;
    const int i0 = blockIdx.x * 24;
    const int jc = blockIdx.y, j0 = jc * 64;
    const int bh = blockIdx.z;

    const f16*   eabb = eab + (size_t)bh * N_ * N_;
    const f16*   ecdb = ecd + (size_t)bh * N_ * N_;
    const f16*   eefb = eef + (size_t)bh * N_ * N_;
    const float* v1b  = v1  + (size_t)bh * N_ * D_;
    const f16*   v2tb = vt2 + (size_t)bh * D_ * N_;

    // ---- stage eEF chunk (rows j0..j0+63, full K), 16B blocks XOR-swizzled
    {
        const int row = tid >> 2;
#pragma unroll
        for (int rep = 0; rep < 12; ++rep) {
            const int kb = (tid & 3) + rep * 4;
            *(uint4*)(eefs + row * 384 + ((kb ^ (row & 7)) << 3)) =
                *(const uint4*)(eefb + (size_t)(j0 + row) * N_ + kb * 8);
        }
    }
    // ---- stage v2 upper k-half: v2s[d][k-192], swizzled same way
    {
        const int row = tid >> 2;
#pragma unroll
        for (int rep = 0; rep < 6; ++rep) {
            const int kb = (tid & 3) + rep * 4;           // 0..23
            *(uint4*)(v2s + row * 192 + ((kb ^ (row & 7)) << 3)) =
                *(const uint4*)(v2tb + (size_t)row * N_ + 192 + kb * 8);
        }
    }
    // ---- v2 register cache for lower k-half: B-frag pieces [dt][ks]
    f16x8 v2f[4][6];
#pragma unroll
    for (int dt = 0; dt < 4; ++dt)
#pragma unroll
        for (int ks = 0; ks < 6; ++ks)
            v2f[dt][ks] = *(const f16x8*)(v2tb + (size_t)(dt * 16 + lr) * N_ +
                                          ks * 32 + quad * 8);
    __syncthreads();
    const int swz = lr & 7;

    for (int t = 0; t < 6; ++t) {
        const int i = i0 + w + t * 4;
        f32x4 acc[4][4];          // [jm][dt]
#pragma unroll
        for (int a = 0; a < 4; ++a)
#pragma unroll
            for (int b = 0; b < 4; ++b)
                acc[a][b] = (f32x4){0.f, 0.f, 0.f, 0.f};

        f16x8 cd_nxt = *(const f16x8*)(ecdb + (size_t)i * N_ + quad * 8);
        // k lower half: v2 from registers
#pragma unroll
        for (int ks = 0; ks < 6; ++ks) {
            const f16x8 cd = cd_nxt;
            cd_nxt = *(const f16x8*)(ecdb + (size_t)i * N_ + (ks + 1) * 32 + quad * 8);
            f16x8 af[4];
#pragma unroll
            for (int jm = 0; jm < 4; ++jm)
                af[jm] = *(const f16x8*)(eefs + (jm * 16 + lr) * 384 +
                                         (((ks * 4 + quad) ^ swz) << 3));
#pragma unroll
            for (int dt = 0; dt < 4; ++dt) {
                const f16x8 bf = cd * v2f[dt][ks];
#pragma unroll
                for (int jm = 0; jm < 4; ++jm)
                    acc[jm][dt] = __builtin_amdgcn_mfma_f32_16x16x32_f16(
                        af[jm], bf, acc[jm][dt], 0, 0, 0);
            }
        }
        // k upper half: v2 from LDS
#pragma unroll
        for (int ks = 6; ks < 12; ++ks) {
            const f16x8 cd = cd_nxt;
            if (ks < 11)
                cd_nxt = *(const f16x8*)(ecdb + (size_t)i * N_ + (ks + 1) * 32 + quad * 8);
            f16x8 af[4], vf[4];
#pragma unroll
            for (int jm = 0; jm < 4; ++jm)
                af[jm] = *(const f16x8*)(eefs + (jm * 16 + lr) * 384 +
                                         (((ks * 4 + quad) ^ swz) << 3));
#pragma unroll
            for (int dt = 0; dt < 4; ++dt)
                vf[dt] = *(const f16x8*)(v2s + (dt * 16 + lr) * 192 +
                                         ((((ks - 6) * 4 + quad) ^ swz) << 3));
#pragma unroll
            for (int dt = 0; dt < 4; ++dt) {
                const f16x8 bf = cd * vf[dt];
#pragma unroll
                for (int jm = 0; jm < 4; ++jm)
                    acc[jm][dt] = __builtin_amdgcn_mfma_f32_16x16x32_f16(
                        af[jm], bf, acc[jm][dt], 0, 0, 0);
            }
        }
        // ---- fold: num[i,d] = sum_j eAB[i,j] * v1[j,d] * Q[j,d]
        f16x4 eabf[4];
#pragma unroll
        for (int jm = 0; jm < 4; ++jm)
            eabf[jm] = *(const f16x4*)(eabb + (size_t)i * N_ + j0 + jm * 16 + quad * 4);
#pragma unroll
        for (int dt = 0; dt < 4; ++dt) {
            float nv = 0.f;
#pragma unroll
            for (int jm = 0; jm < 4; ++jm)
#pragma unroll
                for (int r = 0; r < 4; ++r) {
                    const float v1v = v1b[(size_t)(j0 + jm * 16 + quad * 4 + r) * D_ +
                                          dt * 16 + lr];
                    nv += (float)eabf[jm][r] * v1v * acc[jm][dt][r];
                }
            nv += __shfl_xor(nv, 16);
            nv += __shfl_xor(nv, 32);
            if (lane < 16)
                numw[((size_t)(jc * NBH + bh) * N_ + i) * D_ + dt * 16 + lr] = nv;
        }
    }
}

// ---------------------------------------------------------------------------
// Kernel 3b: denominator. S = eCD·eEF^T (per bh), den[i] = sum_j eAB[i,j]S[i,j].
// Block = (i-tile 64, j-tile 64, bh); wave w owns i-rows w*16..+16.
// ---------------------------------------------------------------------------
__global__ __launch_bounds__(256, 2) void den_kernel(
        const f16* __restrict__ eab,
        const f16* __restrict__ ecd,
        const f16* __restrict__ eef,
        float* __restrict__ denw) {    // [jt][bh][i]
    __shared__ __align__(16) f16 eefs[64 * 384];
    const int tid = threadIdx.x, lane = tid & 63, w = tid >> 6;
    const int quad = lane >> 4, lr = lane & 15;
    const int i0 = blockIdx.x * 64;
    const int jt = blockIdx.y, j0 = jt * 64;
    const int bh = blockIdx.z;
    const f16* eabb = eab + (size_t)bh * N_ * N_;
    const f16* ecdb = ecd + (size_t)bh * N_ * N_;
    const f16* eefb = eef + (size_t)bh * N_ * N_;
    {
        const int row = tid >> 2;
#pragma unroll
        for (int rep = 0; rep < 12; ++rep) {
            const int kb = (tid & 3) + rep * 4;
            *(uint4*)(eefs + row * 384 + ((kb ^ (row & 7)) << 3)) =
                *(const uint4*)(eefb + (size_t)(j0 + row) * N_ + kb * 8);
        }
    }
    __syncthreads();
    const int swz = lr & 7;
    const int irow = i0 + w * 16 + lr;       // A-frag row (m = lr)

    f32x4 acc[4];
#pragma unroll
    for (int a = 0; a < 4; ++a) acc[a] = (f32x4){0.f, 0.f, 0.f, 0.f};
#pragma unroll
    for (int ks = 0; ks < 12; ++ks) {
        const f16x8 aaf = *(const f16x8*)(ecdb + (size_t)irow * N_ + ks * 32 + quad * 8);
#pragma unroll
        for (int jm = 0; jm < 4; ++jm) {
            const f16x8 bfr = *(const f16x8*)(eefs + (jm * 16 + lr) * 384 +
                                              (((ks * 4 + quad) ^ swz) << 3));
            acc[jm] = __builtin_amdgcn_mfma_f32_16x16x32_f16(aaf, bfr, acc[jm], 0, 0, 0);
        }
    }
    float dsum[4] = {0.f, 0.f, 0.f, 0.f};
#pragma unroll
    for (int jm = 0; jm < 4; ++jm)
#pragma unroll
        for (int r = 0; r < 4; ++r)
            dsum[r] += (float)eabb[(size_t)(i0 + w * 16 + quad * 4 + r) * N_ +
                                   j0 + jm * 16 + lr] * acc[jm][r];
#pragma unroll
    for (int r = 0; r < 4; ++r) {
        float v = dsum[r];
        v += __shfl_xor(v, 1);
        v += __shfl_xor(v, 2);
        v += __shfl_xor(v, 4);
        v += __shfl_xor(v, 8);
        if (lr == 0)
            denw[(size_t)(jt * NBH + bh) * N_ + i0 + w * 16 + quad * 4 + r] = v;
    }
}

// ---------------------------------------------------------------------------
// Kernel 4: out = (sum_jc numw) / (sum_jt denw)
// ---------------------------------------------------------------------------
__global__ __launch_bounds__(256) void finalize_kernel(const float* __restrict__ numw,
                                                       const float* __restrict__ denw,
                                                       float* __restrict__ out) {
    const int o = blockIdx.x * 256 + threadIdx.x;
    const int b = o / (N_ * C_);
    const int rem = o - b * (N_ * C_);
    const int n = rem >> 8;
    const int cc = rem & 255;
    const int h = cc >> 6, d = cc & 63;
    const int bh = b * H_ + h;
    float num = 0.f, den = 0.f;
#pragma unroll
    for (int jc = 0; jc < 6; ++jc)
        num += numw[((size_t)(jc * NBH + bh) * N_ + n) * D_ + d];
#pragma unroll
    for (int jt = 0; jt < 6; ++jt)
        den += denw[(size_t)(jt * NBH + bh) * N_ + n];
    out[o] = num / den;
}

extern "C" void kernel_launch(void* const* d_in, const int* in_sizes, int n_in,
                              void* d_out, int out_size, void* d_ws, size_t ws_size,
                              hipStream_t stream) {
    const float* x = (const float*)d_in[0];
    const float* W = (const float*)d_in[1];
    float* ws   = (float*)d_ws;
    float* proj = ws;                               // 5*TSZ f32       (3.93 MB)
    float* numw = ws + 5 * TSZ;                     // 6*8*384*64 f32  (4.72 MB)
    float* denw = numw + 6 * NBH * N_ * D_;         // 6*8*384 f32     (74 KB)
    f16*   eab  = (f16*)(denw + 6 * NBH * N_);      // ESZ f16         (2.25 MB)
    f16*   ecd  = eab + ESZ;
    f16*   eef  = ecd + ESZ;
    f16*   vt2  = eef + ESZ;                        // 8*64*384 f16    (0.38 MB)
    // total ~ 15.9 MB of d_ws

    proj_kernel<<<dim3(12, 20), 256, 0, stream>>>(x, W, proj);
    logits_kernel<<<dim3(6, 6, 24), 256, 0, stream>>>(proj, eab, ecd, eef);
    vtrans_kernel<<<dim3(6, 8), 256, 0, stream>>>(proj, vt2);
    den_kernel<<<dim3(6, 6, 8), 256, 0, stream>>>(eab, ecd, eef, denw);
    triplet_gemm_kernel<<<dim3(16, 6, 8), 256, 0, stream>>>(eab, ecd, eef,
                                                            proj + 3 * TSZ, vt2, numw);
    finalize_kernel<<<dim3(768), 256, 0, stream>>>(numw, denw, (float*)d_out);
}

// Round 6
// 421.845 us; speedup vs baseline: 1.3111x; 1.3111x over previous
//
#include <hip/hip_runtime.h>
#include <math.h>

#define B_  2
#define N_  384
#define C_  256
#define H_  4
#define D_  64
#define NBH (B_*H_)            // 8
#define TSZ (NBH*N_*D_)        // 196608 floats per projected tensor [bh][n][d]
#define ESZ (NBH*N_*N_)        // 1179648 elems per logit matrix
#define SCALE 0.125f           // D^-0.5

typedef _Float16 f16;
typedef f16  f16x8 __attribute__((ext_vector_type(8)));
typedef f16  f16x4 __attribute__((ext_vector_type(4)));
typedef float f32x4 __attribute__((ext_vector_type(4)));

// ---------------------------------------------------------------------------
// Kernel 1: projection. proj[t][bh][n][d], t in {a,b,c,v1,v2}, f32.
// ---------------------------------------------------------------------------
__global__ __launch_bounds__(256) void proj_kernel(const float* __restrict__ x,
                                                   const float* __restrict__ W,
                                                   float* __restrict__ proj) {
    __shared__ float Xs[32][68];
    __shared__ float Ws[32][68];
    const int tid = threadIdx.x;
    const int tx = tid & 15, ty = tid >> 4;
    const int m0 = blockIdx.x * 64;
    const int c0 = blockIdx.y * 64;
    const int t  = c0 >> 8;
    const int wbase = ((t >= 3) ? (t + 3) : t) * 256;

    float acc[4][4] = {{0.f}};
    for (int k0 = 0; k0 < 256; k0 += 32) {
        __syncthreads();
#pragma unroll
        for (int l = 0; l < 8; ++l) {
            const int idx = l * 256 + tid;
            const int mi = idx >> 5, kk = idx & 31;
            Xs[kk][mi] = x[(m0 + mi) * 256 + k0 + kk];
            const int rem = (c0 + mi) & 255;
            Ws[kk][mi] = W[(wbase + rem) * 256 + k0 + kk];
        }
        __syncthreads();
#pragma unroll
        for (int kk = 0; kk < 32; ++kk) {
            const float4 xf = *(const float4*)&Xs[kk][ty * 4];
            const float4 wf = *(const float4*)&Ws[kk][tx * 4];
            const float xa[4] = {xf.x, xf.y, xf.z, xf.w};
            const float wa[4] = {wf.x, wf.y, wf.z, wf.w};
#pragma unroll
            for (int q = 0; q < 4; ++q)
#pragma unroll
                for (int p = 0; p < 4; ++p)
                    acc[q][p] += xa[q] * wa[p];
        }
    }
#pragma unroll
    for (int q = 0; q < 4; ++q) {
        const int r = m0 + ty * 4 + q;
        const int b = r / N_;
        const int n = r - b * N_;
#pragma unroll
        for (int p = 0; p < 4; ++p) {
            const int rem = (c0 + tx * 4 + p) & 255;
            const int h = rem >> 6, d = rem & 63;
            proj[t * TSZ + ((b * H_ + h) * N_ + n) * D_ + d] = acc[q][p];
        }
    }
}

// ---------------------------------------------------------------------------
// Kernel 2: exp-logit matrices, f16, natural [row][col] layouts.
//  q=0: eAB[bh][i][j]   q=1: eCD[bh][i][k]   q=2: eEF[bh][j][k]
// ---------------------------------------------------------------------------
__global__ __launch_bounds__(256) void logits_kernel(const float* __restrict__ proj,
                                                     f16* __restrict__ eab16,
                                                     f16* __restrict__ ecd16,
                                                     f16* __restrict__ eef16) {
    __shared__ float Xs[32][68];
    __shared__ float Ys[32][68];
    const int tid = threadIdx.x;
    const int tx = tid & 15, ty = tid >> 4;
    const int i0 = blockIdx.x * 64, j0 = blockIdx.y * 64;
    const int q  = blockIdx.z >> 3;
    const int bh = blockIdx.z & 7;
    const int xt = q;
    const int yt = (q == 2) ? 0 : (q + 1);
    const float* Xp = proj + xt * TSZ + bh * N_ * D_;
    const float* Yp = proj + yt * TSZ + bh * N_ * D_;

    float acc[4][4] = {{0.f}};
    for (int k0 = 0; k0 < 64; k0 += 32) {
        __syncthreads();
#pragma unroll
        for (int l = 0; l < 8; ++l) {
            const int idx = l * 256 + tid;
            const int mi = idx >> 5, kk = idx & 31;
            Xs[kk][mi] = Xp[(i0 + mi) * 64 + k0 + kk];
            Ys[kk][mi] = Yp[(j0 + mi) * 64 + k0 + kk];
        }
        __syncthreads();
#pragma unroll
        for (int kk = 0; kk < 32; ++kk) {
            const float4 xf = *(const float4*)&Xs[kk][ty * 4];
            const float4 yf = *(const float4*)&Ys[kk][tx * 4];
            const float xa[4] = {xf.x, xf.y, xf.z, xf.w};
            const float ya[4] = {yf.x, yf.y, yf.z, yf.w};
#pragma unroll
            for (int qq = 0; qq < 4; ++qq)
#pragma unroll
                for (int p = 0; p < 4; ++p)
                    acc[qq][p] += xa[qq] * ya[p];
        }
    }
#pragma unroll
    for (int qq = 0; qq < 4; ++qq)
#pragma unroll
        for (int p = 0; p < 4; ++p) {
            const float e = expf(acc[qq][p] * SCALE);
            const size_t o = (size_t)bh * N_ * N_ + (i0 + ty * 4 + qq) * N_ + j0 + tx * 4 + p;
            if (q == 0)      eab16[o] = (f16)e;
            else if (q == 1) ecd16[o] = (f16)e;
            else             eef16[o] = (f16)e;
        }
}

// ---------------------------------------------------------------------------
// Kernel 2b: transpose v1 -> vt1[bh][d][n] f32 (z=0) and v2 -> vt2 f16 (z=1).
// ---------------------------------------------------------------------------
__global__ __launch_bounds__(256) void vtrans_kernel(const float* __restrict__ proj,
                                                     float* __restrict__ vt1,
                                                     f16* __restrict__ vt2) {
    __shared__ float tile[64][65];
    const int tid = threadIdx.x;
    const int n0 = blockIdx.x * 64;
    const int bh = blockIdx.y;
    const int t  = blockIdx.z;               // 0: v1 (f32 out), 1: v2 (f16 out)
    const float* src = proj + (3 + t) * TSZ + ((size_t)bh * N_ + n0) * 64;
#pragma unroll
    for (int rep = 0; rep < 16; ++rep) {
        const int idx = rep * 256 + tid;
        const int r = idx >> 6, d = idx & 63;
        tile[d][r] = src[r * 64 + d];
    }
    __syncthreads();
#pragma unroll
    for (int rep = 0; rep < 16; ++rep) {
        const int idx = rep * 256 + tid;
        const int d = idx >> 6, c = idx & 63;
        if (t == 0) vt1[((size_t)bh * 64 + d) * N_ + n0 + c] = tile[d][c];
        else        vt2[((size_t)bh * 64 + d) * N_ + n0 + c] = (f16)tile[d][c];
    }
}

// ---------------------------------------------------------------------------
// Kernel 3 (dominant): Q_i[j,d] = sum_k eEF[j,k] * (eCD[i,k]*v2[k,d]),
// d in the MFMA N-dim. Block = (i-chunk 24, j-chunk 64, bh).
// K processed in 2 halves of 192: eefs(24KB) + v2s(24KB) = 48KB -> 3 blk/CU.
// All B-operand inputs from LDS (v2) or broadcast regs (cdh[6], 24 VGPR).
// Fold is linear in Q -> fold each half immediately; kh=1 accumulates via
// same-thread global RMW. Register budget ~145, launch_bounds(256,3).
// ---------------------------------------------------------------------------
__global__ __launch_bounds__(256, 3) void triplet_gemm_kernel(
        const f16* __restrict__ eab,   // [bh][i][j]
        const f16* __restrict__ ecd,   // [bh][i][k]
        const f16* __restrict__ eef,   // [bh][j][k]
        const float* __restrict__ vt1, // [bh][d][n] f32
        const f16* __restrict__ vt2,   // [bh][d][n] f16
        float* __restrict__ numw) {    // [jc][bh][i][64]
    __shared__ __align__(16) f16 eefs[64 * 192];   // 24 KB
    __shared__ __align__(16) f16 v2s[64 * 192];    // 24 KB

    const int tid = threadIdx.x, lane = tid & 63, w = tid >> 6;
    const int quad = lane >> 4, lr = lane & 15;
    const int i0 = blockIdx.x * 24;
    const int jc = blockIdx.y, j0 = jc * 64;
    const int bh = blockIdx.z;

    const f16*   eabb = eab + (size_t)bh * N_ * N_;
    const f16*   ecdb = ecd + (size_t)bh * N_ * N_;
    const f16*   eefb = eef + (size_t)bh * N_ * N_;
    const float* vt1b = vt1 + (size_t)bh * D_ * N_;
    const f16*   vt2b = vt2 + (size_t)bh * D_ * N_;
    const int swz = lr & 7;

    for (int kh = 0; kh < 2; ++kh) {
        const int kbase = kh * 192;
        __syncthreads();                 // prior half's LDS readers done
        {
            const int row = tid >> 2;
#pragma unroll
            for (int rep = 0; rep < 6; ++rep) {
                const int kb = (tid & 3) + rep * 4;          // 0..23 octets
                const int dsto = ((kb ^ (row & 7)) << 3);
                *(uint4*)(eefs + row * 192 + dsto) =
                    *(const uint4*)(eefb + (size_t)(j0 + row) * N_ + kbase + kb * 8);
                *(uint4*)(v2s + row * 192 + dsto) =
                    *(const uint4*)(vt2b + (size_t)row * N_ + kbase + kb * 8);
            }
        }
        __syncthreads();

        for (int t = 0; t < 6; ++t) {
            const int i = i0 + w + t * 4;
            // batched broadcast preload of eCD row-i frags for this half
            f16x8 cdh[6];
#pragma unroll
            for (int ks = 0; ks < 6; ++ks)
                cdh[ks] = *(const f16x8*)(ecdb + (size_t)i * N_ + kbase + ks * 32 + quad * 8);

            f32x4 acc[4][4];          // [jm][dt]
#pragma unroll
            for (int a = 0; a < 4; ++a)
#pragma unroll
                for (int b = 0; b < 4; ++b)
                    acc[a][b] = (f32x4){0.f, 0.f, 0.f, 0.f};

#pragma unroll
            for (int ks = 0; ks < 6; ++ks) {
                const int oct = ((ks * 4 + quad) ^ swz) << 3;
                f16x8 af[4];
#pragma unroll
                for (int jm = 0; jm < 4; ++jm)
                    af[jm] = *(const f16x8*)(eefs + (jm * 16 + lr) * 192 + oct);
#pragma unroll
                for (int dt = 0; dt < 4; ++dt) {
                    const f16x8 vf = *(const f16x8*)(v2s + (dt * 16 + lr) * 192 + oct);
                    const f16x8 bf = cdh[ks] * vf;        // v_pk_mul_f16 x4
#pragma unroll
                    for (int jm = 0; jm < 4; ++jm)
                        acc[jm][dt] = __builtin_amdgcn_mfma_f32_16x16x32_f16(
                            af[jm], bf, acc[jm][dt], 0, 0, 0);
                }
            }
            // ---- fold this half: num[i,d] += sum_j eAB[i,j]*v1[j,d]*Q[j,d]
            f16x4 eabf[4];
#pragma unroll
            for (int jm = 0; jm < 4; ++jm)
                eabf[jm] = *(const f16x4*)(eabb + (size_t)i * N_ + j0 + jm * 16 + quad * 4);
#pragma unroll
            for (int dt = 0; dt < 4; ++dt) {
                float nv = 0.f;
#pragma unroll
                for (int jm = 0; jm < 4; ++jm) {
                    const float4 v1q = *(const float4*)(vt1b + (size_t)(dt * 16 + lr) * N_ +
                                                        j0 + jm * 16 + quad * 4);
                    nv += (float)eabf[jm][0] * v1q.x * acc[jm][dt][0]
                        + (float)eabf[jm][1] * v1q.y * acc[jm][dt][1]
                        + (float)eabf[jm][2] * v1q.z * acc[jm][dt][2]
                        + (float)eabf[jm][3] * v1q.w * acc[jm][dt][3];
                }
                nv += __shfl_xor(nv, 16);
                nv += __shfl_xor(nv, 32);
                if (lane < 16) {
                    float* dst = &numw[((size_t)(jc * NBH + bh) * N_ + i) * D_ + dt * 16 + lr];
                    if (kh == 0) *dst = nv;       // same thread writes kh=0,
                    else         *dst += nv;      // reads+adds kh=1: ordered
                }
            }
        }
    }
}

// ---------------------------------------------------------------------------
// Kernel 3b: denominator. S = eCD·eEF^T, den[i] = sum_j eAB[i,j]*S[i,j].
// ---------------------------------------------------------------------------
__global__ __launch_bounds__(256, 2) void den_kernel(
        const f16* __restrict__ eab,
        const f16* __restrict__ ecd,
        const f16* __restrict__ eef,
        float* __restrict__ denw) {    // [jt][bh][i]
    __shared__ __align__(16) f16 eefs[64 * 384];
    const int tid = threadIdx.x, lane = tid & 63, w = tid >> 6;
    const int quad = lane >> 4, lr = lane & 15;
    const int i0 = blockIdx.x * 64;
    const int jt = blockIdx.y, j0 = jt * 64;
    const int bh = blockIdx.z;
    const f16* eabb = eab + (size_t)bh * N_ * N_;
    const f16* ecdb = ecd + (size_t)bh * N_ * N_;
    const f16* eefb = eef + (size_t)bh * N_ * N_;
    {
        const int row = tid >> 2;
#pragma unroll
        for (int rep = 0; rep < 12; ++rep) {
            const int kb = (tid & 3) + rep * 4;
            *(uint4*)(eefs + row * 384 + ((kb ^ (row & 7)) << 3)) =
                *(const uint4*)(eefb + (size_t)(j0 + row) * N_ + kb * 8);
        }
    }
    __syncthreads();
    const int swz = lr & 7;
    const int irow = i0 + w * 16 + lr;

    f32x4 acc[4];
#pragma unroll
    for (int a = 0; a < 4; ++a) acc[a] = (f32x4){0.f, 0.f, 0.f, 0.f};
#pragma unroll
    for (int ks = 0; ks < 12; ++ks) {
        const f16x8 aaf = *(const f16x8*)(ecdb + (size_t)irow * N_ + ks * 32 + quad * 8);
#pragma unroll
        for (int jm = 0; jm < 4; ++jm) {
            const f16x8 bfr = *(const f16x8*)(eefs + (jm * 16 + lr) * 384 +
                                              (((ks * 4 + quad) ^ swz) << 3));
            acc[jm] = __builtin_amdgcn_mfma_f32_16x16x32_f16(aaf, bfr, acc[jm], 0, 0, 0);
        }
    }
    float dsum[4] = {0.f, 0.f, 0.f, 0.f};
#pragma unroll
    for (int jm = 0; jm < 4; ++jm)
#pragma unroll
        for (int r = 0; r < 4; ++r)
            dsum[r] += (float)eabb[(size_t)(i0 + w * 16 + quad * 4 + r) * N_ +
                                   j0 + jm * 16 + lr] * acc[jm][r];
#pragma unroll
    for (int r = 0; r < 4; ++r) {
        float v = dsum[r];
        v += __shfl_xor(v, 1);
        v += __shfl_xor(v, 2);
        v += __shfl_xor(v, 4);
        v += __shfl_xor(v, 8);
        if (lr == 0)
            denw[(size_t)(jt * NBH + bh) * N_ + i0 + w * 16 + quad * 4 + r] = v;
    }
}

// ---------------------------------------------------------------------------
// Kernel 4: out = (sum_jc numw) / (sum_jt denw)
// ---------------------------------------------------------------------------
__global__ __launch_bounds__(256) void finalize_kernel(const float* __restrict__ numw,
                                                       const float* __restrict__ denw,
                                                       float* __restrict__ out) {
    const int o = blockIdx.x * 256 + threadIdx.x;
    const int b = o / (N_ * C_);
    const int rem = o - b * (N_ * C_);
    const int n = rem >> 8;
    const int cc = rem & 255;
    const int h = cc >> 6, d = cc & 63;
    const int bh = b * H_ + h;
    float num = 0.f, den = 0.f;
#pragma unroll
    for (int jc = 0; jc < 6; ++jc)
        num += numw[((size_t)(jc * NBH + bh) * N_ + n) * D_ + d];
#pragma unroll
    for (int jt = 0; jt < 6; ++jt)
        den += denw[(size_t)(jt * NBH + bh) * N_ + n];
    out[o] = num / den;
}

extern "C" void kernel_launch(void* const* d_in, const int* in_sizes, int n_in,
                              void* d_out, int out_size, void* d_ws, size_t ws_size,
                              hipStream_t stream) {
    const float* x = (const float*)d_in[0];
    const float* W = (const float*)d_in[1];
    float* ws   = (float*)d_ws;
    float* proj = ws;                               // 5*TSZ f32       (3.93 MB)
    float* numw = ws + 5 * TSZ;                     // 6*8*384*64 f32  (4.72 MB)
    float* denw = numw + 6 * NBH * N_ * D_;         // 6*8*384 f32     (74 KB)
    float* vt1  = denw + 6 * NBH * N_;              // 8*64*384 f32    (0.79 MB)
    f16*   eab  = (f16*)(vt1 + TSZ);                // ESZ f16         (2.25 MB)
    f16*   ecd  = eab + ESZ;
    f16*   eef  = ecd + ESZ;
    f16*   vt2  = eef + ESZ;                        // 8*64*384 f16    (0.38 MB)
    // total ~ 17 MB of d_ws

    proj_kernel<<<dim3(12, 20), 256, 0, stream>>>(x, W, proj);
    logits_kernel<<<dim3(6, 6, 24), 256, 0, stream>>>(proj, eab, ecd, eef);
    vtrans_kernel<<<dim3(6, 8, 2), 256, 0, stream>>>(proj, vt1, vt2);
    den_kernel<<<dim3(6, 6, 8), 256, 0, stream>>>(eab, ecd, eef, denw);
    triplet_gemm_kernel<<<dim3(16, 6, 8), 256, 0, stream>>>(eab, ecd, eef,
                                                            vt1, vt2, numw);
    finalize_kernel<<<dim3(768), 256, 0, stream>>>(numw, denw, (float*)d_out);
}